// Round 11
// baseline (828.747 us; speedup 1.0000x reference)
//
#include <hip/hip_runtime.h>

#define NN 50000
#define NE 800000

typedef unsigned short u16;
typedef __bf16 bf16x8 __attribute__((ext_vector_type(8)));
typedef float f32x4 __attribute__((ext_vector_type(4)));
typedef unsigned short u16x8 __attribute__((ext_vector_type(8)));

// native RNE bf16 convert: single v_cvt (pairs get packed to v_cvt_pk_bf16_f32).
__device__ __forceinline__ u16 f2b(float f){
  return __builtin_bit_cast(u16, (__bf16)f);
}
__device__ __forceinline__ float b2f(u16 b){
  return __uint_as_float(((unsigned)b)<<16);
}
// sum over each 16-lane DPP row via rotate-reduce: 4 VALU adds, no LDS pipe.
__device__ __forceinline__ float row_sum16(float x){
  x += __int_as_float(__builtin_amdgcn_update_dpp(0, __float_as_int(x), 0x121, 0xF, 0xF, true));
  x += __int_as_float(__builtin_amdgcn_update_dpp(0, __float_as_int(x), 0x122, 0xF, 0xF, true));
  x += __int_as_float(__builtin_amdgcn_update_dpp(0, __float_as_int(x), 0x124, 0xF, 0xF, true));
  x += __int_as_float(__builtin_amdgcn_update_dpp(0, __float_as_int(x), 0x128, 0xF, 0xF, true));
  return x;
}
#define MFMA16(a,b,c) __builtin_amdgcn_mfma_f32_16x16x32_bf16((a),(b),(c),0,0,0)

// ---------------- K0: weights->bf16 [n][k] + edge histogram (fused) ---------
__global__ void k_prep_hist(const float* __restrict__ w1, const float* __restrict__ w2,
                            const float* __restrict__ w3, const float* __restrict__ wsep,
                            const float* __restrict__ wsrc, const float* __restrict__ wdst,
                            const float* __restrict__ wproj,
                            u16* __restrict__ w1T, u16* __restrict__ w2T,
                            u16* __restrict__ w3T, u16* __restrict__ wsepT,
                            u16* __restrict__ wsrcT, u16* __restrict__ wdstT,
                            u16* __restrict__ wprojT,
                            const int* __restrict__ edst, unsigned* __restrict__ cnt)
{
  if (blockIdx.x < 376){
    int id = blockIdx.x*256 + threadIdx.x;
    if (id < 2048)  { int n=id>>5,  k=id&31;  w1T[id]   = f2b(w1[k*64+n]);    return; } id -= 2048;
    if (id < 4096)  { int n=id>>6,  k=id&63;  w2T[id]   = f2b(w2[k*64+n]);    return; } id -= 4096;
    if (id < 8192)  { int n=id>>6,  k=id&63;  w3T[id]   = f2b(w3[k*128+n]);   return; } id -= 8192;
    if (id < 32768) { int n=id>>7,  k=id&127; wsepT[id] = f2b(wsep[k*256+n]); return; } id -= 32768;
    if (id < 16384) { int n=id>>7,  k=id&127; wsrcT[id] = f2b(wsrc[k*128+n]); return; } id -= 16384;
    if (id < 16384) { int n=id>>7,  k=id&127; wdstT[id] = f2b(wdst[k*128+n]); return; } id -= 16384;
    if (id < 16384) { int n=id>>7,  k=id&127; wprojT[id]= f2b(wproj[k*128+n]); return; }
    return;
  }
  int e = (blockIdx.x - 376)*256 + threadIdx.x;
  if (e < NE) atomicAdd(&cnt[edst[e]], 1u);
}

// ---------------- parallel scan ---------------------------------------------
__launch_bounds__(1024)
__global__ void k_scan1(const unsigned* __restrict__ cnt, unsigned* __restrict__ cur,
                        unsigned* __restrict__ btot)
{
  __shared__ unsigned wt[16];
  const int tid = threadIdx.x, lane = tid&63, w = tid>>6;
  int i = blockIdx.x*1024 + tid;
  unsigned v = (i < NN) ? cnt[i] : 0u;
  unsigned x = v;
  #pragma unroll
  for (int off=1; off<64; off<<=1){
    unsigned t = __shfl_up(x, off);
    if (lane >= off) x += t;
  }
  if (lane == 63) wt[w] = x;
  __syncthreads();
  if (w == 0){
    unsigned y = (lane < 16) ? wt[lane] : 0u;
    #pragma unroll
    for (int off=1; off<16; off<<=1){
      unsigned t = __shfl_up(y, off);
      if (lane >= off) y += t;
    }
    if (lane < 16) wt[lane] = y;        // inclusive scan of wave totals
  }
  __syncthreads();
  unsigned wo = w ? wt[w-1] : 0u;
  if (i < NN) cur[i] = wo + (x - v);    // block-local exclusive prefix
  if (tid == 1023) btot[blockIdx.x] = wo + x;
}

__global__ void k_scan2(unsigned* __restrict__ btot)
{
  int lane = threadIdx.x;               // single wave of 64
  unsigned v = (lane < 49) ? btot[lane] : 0u;
  unsigned x = v;
  #pragma unroll
  for (int off=1; off<64; off<<=1){
    unsigned t = __shfl_up(x, off);
    if (lane >= off) x += t;
  }
  if (lane < 49) btot[lane] = x - v;    // exclusive, in-place
}

// ---------------- scatter (sort) + node GEMM (fused, independent work) ------
// blocks [0,3125): counting-sort scatter (memory-random). blocks [3125,3907):
// node GEMM (MFMA-heavy). Fusing makes them CONCURRENT instead of serial.
// Node GEMM reads weights directly from global (L2-resident broadcast) —
// no sW staging, LDS 52.7KB -> 17.9KB.
__launch_bounds__(256)
__global__ void k_scatter_node(const int* __restrict__ esrc, const int* __restrict__ edst,
                               const float* __restrict__ eattr, unsigned* __restrict__ cur,
                               const unsigned* __restrict__ btot, int4* __restrict__ ework,
                               const float* __restrict__ x, const u16* __restrict__ wsrcT,
                               const u16* __restrict__ wdstT, const float* __restrict__ bsrc,
                               u16* __restrict__ msgsrcB, u16* __restrict__ msgdstB)
{
  __shared__ u16 sX[64*136];
  const int tid = threadIdx.x;
  if (blockIdx.x < 3125){
    int e = blockIdx.x*256 + tid;
    if (e < NE){
      int d = edst[e];
      unsigned pos = btot[d>>10] + atomicAdd(&cur[d], 1u);
      ework[pos] = make_int4(e, d, esrc[e], __float_as_int(eattr[e]));
    }
    return;
  }
  const int n0 = (blockIdx.x - 3125)*64;
  for (int idx = tid; idx < 64*32; idx += 256){
    int r = idx>>5, s = idx&31;
    float4 v = make_float4(0.f,0.f,0.f,0.f);
    if (n0 + r < NN) v = *(const float4*)(x + (size_t)(n0+r)*128 + s*4);
    ushort4 o; o.x=f2b(v.x); o.y=f2b(v.y); o.z=f2b(v.z); o.w=f2b(v.w);
    *(ushort4*)(&sX[r*136 + s*4]) = o;
  }
  __syncthreads();
  const int wave = tid>>6, lane = tid&63, l15 = lane&15, q = lane>>4;
  for (int half = 0; half < 2; ++half){
    const u16* wT = half ? wdstT : wsrcT;
    f32x4 acc[8];
    #pragma unroll
    for (int n=0;n<8;++n) acc[n] = (f32x4){0.f,0.f,0.f,0.f};
    #pragma unroll
    for (int k0=0;k0<128;k0+=32){
      bf16x8 a = *(const bf16x8*)(&sX[(wave*16+l15)*136 + k0 + q*8]);
      #pragma unroll
      for (int n=0;n<8;++n){
        bf16x8 b = *(const bf16x8*)(wT + (n*16+l15)*128 + k0 + q*8);
        acc[n] = MFMA16(a,b,acc[n]);
      }
    }
    u16* outp = half ? msgdstB : msgsrcB;
    #pragma unroll
    for (int n=0;n<8;++n){
      float bia = half ? 0.0f : bsrc[n*16+l15];
      #pragma unroll
      for (int r=0;r<4;++r){
        int row = n0 + wave*16 + q*4 + r;
        if (row < NN) outp[(size_t)row*128 + n*16 + l15] = f2b(acc[n][r] + bia);
      }
    }
  }
}

// ---------------- K2: fused edge kernel (dst-sorted order) ------------------
// v12 = v9 (known-good 455us) + phase-E msgsrc PREFETCH: the random L3 gather
// is issued at kernel start so its ~700cy latency hides under phases A-D.
// All barriers unchanged (block lockstep preserved — the property v5/v8 lost).
#define PM 136
#define PH 72
#define PX 40
__launch_bounds__(256,6)
__global__ void k_edge(const float* __restrict__ escal, const int4* __restrict__ ework,
                       const u16* __restrict__ msgsrcB, const u16* __restrict__ msgdstB,
                       const u16* __restrict__ w1T, const u16* __restrict__ w2T,
                       const u16* __restrict__ w3T, const u16* __restrict__ wsepT,
                       const float* __restrict__ b1, const float* __restrict__ b2,
                       const float* __restrict__ b3, const float* __restrict__ bsep,
                       const float* __restrict__ adot,
                       float* __restrict__ num, float* __restrict__ denom)
{
  // liveness-overlaid pool (26624 B -> 6 blocks/CU):
  //   sH1  [0,9216)      written B, read C
  //   sXs  [9216,14336)  written A, read B
  //   sH2  [17408,26624) written C, read D; phase F reuses as sWV[64][34] f32
  //                      (8704 B) + sWp[64][2] f32 (512 B) = 9216 B exactly
  //   sMsg [0,17408)     written D, E in-place, read F
  __shared__ __attribute__((aligned(16))) char pool[26624];
  u16* sH1  = (u16*)(pool + 0);
  u16* sXs  = (u16*)(pool + 9216);
  u16* sH2  = (u16*)(pool + 17408);
  u16* sMsg = (u16*)(pool + 0);

  const int tid = threadIdx.x;
  const int e0 = blockIdx.x*64;
  const int wave = tid>>6, lane = tid&63, l15 = lane&15, q = lane>>4;

  // ---- prefetch: issue phase-E's random msgsrc gather NOW (consumed in E).
  // Addresses depend only on ework; latency hides under phases A-D.
  u16x8 pf[4];
  int   pid[4];
  float pea[4];
  #pragma unroll
  for (int t=0;t<4;++t){
    int idx = tid + t*256;
    int r = idx>>4, s = idx&15;
    int4 em = ework[e0 + r];
    pf[t]  = *(const u16x8*)(msgsrcB + (size_t)em.z*128 + s*8);
    pid[t] = em.y;
    pea[t] = __int_as_float(em.w);
  }

  // ---- phase A: stage edge scalars (permuted gather, fp32->bf16)
  for (int j = tid; j < 512; j += 256){ int r=j>>3, s=j&7;
    int pe = ework[e0 + r].x;
    float4 v = *(const float4*)(escal + (size_t)pe*32 + s*4);
    ushort4 o; o.x=f2b(v.x); o.y=f2b(v.y); o.z=f2b(v.z); o.w=f2b(v.w);
    *(ushort4*)&sXs[r*PX + s*4] = o; }
  __syncthreads();

  // ---- phase B: MLP layer1 (K=32) + silu -> sH1 (weights from global)
  {
    f32x4 acc[4];
    #pragma unroll
    for (int n=0;n<4;++n) acc[n] = (f32x4){0.f,0.f,0.f,0.f};
    bf16x8 a = *(const bf16x8*)&sXs[(wave*16+l15)*PX + q*8];
    #pragma unroll
    for (int n=0;n<4;++n){
      bf16x8 b = *(const bf16x8*)(w1T + (n*16+l15)*32 + q*8);
      acc[n] = MFMA16(a,b,acc[n]);
    }
    #pragma unroll
    for (int n=0;n<4;++n){
      float bia = b1[n*16+l15];
      #pragma unroll
      for (int r=0;r<4;++r){
        float v = acc[n][r] + bia;
        float h = v / (1.0f + __expf(-v));
        sH1[(wave*16+q*4+r)*PH + n*16+l15] = f2b(h);
      }
    }
  }
  __syncthreads();

  // ---- phase C: MLP layer2 (K=64) + silu -> sH2 (weights from global)
  {
    f32x4 acc[4];
    #pragma unroll
    for (int n=0;n<4;++n) acc[n] = (f32x4){0.f,0.f,0.f,0.f};
    #pragma unroll
    for (int k0=0;k0<64;k0+=32){
      bf16x8 a = *(const bf16x8*)&sH1[(wave*16+l15)*PH + k0 + q*8];
      #pragma unroll
      for (int n=0;n<4;++n){
        bf16x8 b = *(const bf16x8*)(w2T + (n*16+l15)*64 + k0 + q*8);
        acc[n] = MFMA16(a,b,acc[n]);
      }
    }
    #pragma unroll
    for (int n=0;n<4;++n){
      float bia = b2[n*16+l15];
      #pragma unroll
      for (int r=0;r<4;++r){
        float v = acc[n][r] + bia;
        float h = v / (1.0f + __expf(-v));
        sH2[(wave*16+q*4+r)*PH + n*16+l15] = f2b(h);
      }
    }
  }
  __syncthreads();

  // ---- phase D: MLP layer3 (K=64, 2 chunks of 64 cols) -> rad_w into sMsg
  {
    const int m0 = (wave&1)*2, n0 = (wave>>1)*2;
    #pragma unroll
    for (int ch=0; ch<2; ++ch){
      f32x4 acc[2][2];
      #pragma unroll
      for (int mm=0;mm<2;++mm)
        #pragma unroll
        for (int nn=0;nn<2;++nn) acc[mm][nn] = (f32x4){0.f,0.f,0.f,0.f};
      const u16* w3b = w3T + (size_t)(ch*64)*64;
      #pragma unroll
      for (int k0=0;k0<64;k0+=32){
        bf16x8 a0 = *(const bf16x8*)&sH2[((m0  )*16+l15)*PH + k0 + q*8];
        bf16x8 a1 = *(const bf16x8*)&sH2[((m0+1)*16+l15)*PH + k0 + q*8];
        bf16x8 bb0 = *(const bf16x8*)(w3b + ((n0  )*16+l15)*64 + k0 + q*8);
        bf16x8 bb1 = *(const bf16x8*)(w3b + ((n0+1)*16+l15)*64 + k0 + q*8);
        acc[0][0] = MFMA16(a0,bb0,acc[0][0]);
        acc[1][0] = MFMA16(a1,bb0,acc[1][0]);
        acc[0][1] = MFMA16(a0,bb1,acc[0][1]);
        acc[1][1] = MFMA16(a1,bb1,acc[1][1]);
      }
      #pragma unroll
      for (int mm=0;mm<2;++mm){
        #pragma unroll
        for (int nn=0;nn<2;++nn){
          int c = ch*64 + (n0+nn)*16 + l15;
          float bia = b3[c];
          #pragma unroll
          for (int r=0;r<4;++r){
            float v = acc[mm][nn][r] + bia;
            sMsg[((m0+mm)*16+q*4+r)*PM + c] = f2b(v);
          }
        }
      }
    }
  }
  __syncthreads();

  // ---- phase E: combine prefetched msgsrc + sorted msgdst + rad_w (in-place)
  #pragma unroll
  for (int t=0;t<4;++t){
    int idx = tid + t*256;
    int r = idx>>4, s = idx&15;
    int cs = s*8;
    u16x8 d8 = *(const u16x8*)(msgdstB + (size_t)pid[t]*128 + cs);
    float ea = pea[t];
    u16x8 rw = *(const u16x8*)&sMsg[r*PM + cs];
    u16x8 o;
    #pragma unroll
    for (int j=0;j<8;++j){
      o[j] = f2b((b2f(pf[t][j]) + b2f(d8[j])) * ea * b2f(rw[j]));
    }
    *(u16x8*)&sMsg[r*PM + cs] = o;
  }
  __syncthreads();

  // ---- phase F: message @ w_sep, score->w, then SEGMENTED walk + atomics.
  // No max-subtraction: |score| <~ 5 analytically, exp() safe in fp32, and
  // exp(m) cancels between numerator and denominator as in the reference.
  {
    const int fm0 = (wave&1)*2, fn0 = (wave>>1)*2;
    const int hh = fn0>>1;                      // which head of the ch-pair
    float* sWV = (float*)(pool + 17408);        // [64][34] w*vv (value cols)
    float* sWp = (float*)(pool + 17408 + 8704); // [64][2]  w per (edge, hh)
    const u16* wb0 = wsepT + (size_t)((fn0  )*16+l15)*128 + q*8;
    const u16* wb1 = wsepT + (size_t)((fn0+1)*16+l15)*128 + q*8;
    // walk-role mapping: 8 row-groups x 32 value cols
    const int wc = tid & 31, wg = tid >> 5, wcl = wc & 15, whh = wc >> 4;
    int dreg[8];
    #pragma unroll
    for (int rr=0; rr<8; ++rr) dreg[rr] = ework[e0 + wg*8 + rr].y;

    #pragma unroll
    for (int ch=0; ch<4; ++ch){
      f32x4 acc[2][2];   // [mm][0]=alpha subtile, [mm][1]=value subtile
      #pragma unroll
      for (int mm=0;mm<2;++mm)
        #pragma unroll
        for (int nn=0;nn<2;++nn) acc[mm][nn] = (f32x4){0.f,0.f,0.f,0.f};
      #pragma unroll
      for (int k0=0;k0<128;k0+=32){
        bf16x8 a0 = *(const bf16x8*)&sMsg[((fm0  )*16+l15)*PM + k0 + q*8];
        bf16x8 a1 = *(const bf16x8*)&sMsg[((fm0+1)*16+l15)*PM + k0 + q*8];
        bf16x8 bb0 = *(const bf16x8*)(wb0 + (size_t)ch*64*128 + k0);
        bf16x8 bb1 = *(const bf16x8*)(wb1 + (size_t)ch*64*128 + k0);
        acc[0][0] = MFMA16(a0,bb0,acc[0][0]);
        acc[1][0] = MFMA16(a1,bb0,acc[1][0]);
        acc[0][1] = MFMA16(a0,bb1,acc[0][1]);
        acc[1][1] = MFMA16(a1,bb1,acc[1][1]);
      }
      {
        const int h  = ch*2 + hh;
        const int ca = ch*64 + fn0*16;
        const float ba = bsep[ca + l15];
        const float bv = bsep[ca + 16 + l15];
        const float ad = adot[h*16 + l15];
        #pragma unroll
        for (int mm=0;mm<2;++mm){
          #pragma unroll
          for (int r=0;r<4;++r){
            float av  = acc[mm][0][r] + ba;
            float sig = 1.0f/(1.0f + __expf(-av));
            float sl  = av*(0.2f + 0.8f*sig);       // smooth_leaky_relu(a=0.2)
            float contrib = row_sum16(sl * ad);     // DPP rotate-reduce
            float w  = __expf(contrib);
            float vv = acc[mm][1][r] + bv;
            int row  = (fm0+mm)*16 + q*4 + r;
            sWV[row*34 + hh*16 + l15] = w*vv;
            if (l15 == 0) sWp[row*2 + hh] = w;
          }
        }
      }
      __syncthreads();
      // segmented walk: each thread owns (8-row group, 1 value col); merge
      // runs of equal dst (sorted!) before atomic.
      {
        const int h = ch*2 + whh;
        float av = 0.f, wa = 0.f;
        int pd = dreg[0];
        #pragma unroll
        for (int rr=0; rr<8; ++rr){
          int d = dreg[rr];
          if (d != pd){
            unsafeAtomicAdd(&num[(size_t)pd*128 + h*16 + wcl], av);
            if (wcl == 0) unsafeAtomicAdd(&denom[(size_t)pd*8 + h], wa);
            av = 0.f; wa = 0.f; pd = d;
          }
          int row = wg*8 + rr;
          av += sWV[row*34 + wc];
          if (wcl == 0) wa += sWp[row*2 + whh];
        }
        unsafeAtomicAdd(&num[(size_t)pd*128 + h*16 + wcl], av);
        if (wcl == 0) unsafeAtomicAdd(&denom[(size_t)pd*8 + h], wa);
      }
      __syncthreads();
    }
  }
}

// ---------------- K3: normalize + output projection (weights from global) ---
__launch_bounds__(256)
__global__ void k_out(const float* __restrict__ num, const float* __restrict__ denom,
                      const u16* __restrict__ wprojT, const float* __restrict__ bproj,
                      float* __restrict__ out)
{
  __shared__ u16 sX[64*136];
  const int tid = threadIdx.x;
  const int n0 = blockIdx.x*64;
  for (int idx = tid; idx < 64*128; idx += 256){
    int r = idx>>7, c = idx&127;
    float xv = 0.f;
    int row = n0 + r;
    if (row < NN){
      float d = denom[row*8 + (c>>4)];
      xv = num[(size_t)row*128 + c] / (d + 1e-16f);
    }
    sX[r*136 + c] = f2b(xv);
  }
  __syncthreads();
  const int wave = tid>>6, lane = tid&63, l15 = lane&15, q = lane>>4;
  f32x4 acc[8];
  #pragma unroll
  for (int n=0;n<8;++n) acc[n] = (f32x4){0.f,0.f,0.f,0.f};
  #pragma unroll
  for (int k0=0;k0<128;k0+=32){
    bf16x8 a = *(const bf16x8*)&sX[(wave*16+l15)*136 + k0 + q*8];
    #pragma unroll
    for (int n=0;n<8;++n){
      bf16x8 b = *(const bf16x8*)(wprojT + (n*16+l15)*128 + k0 + q*8);
      acc[n] = MFMA16(a,b,acc[n]);
    }
  }
  #pragma unroll
  for (int n=0;n<8;++n){
    float bia = bproj[n*16+l15];
    #pragma unroll
    for (int r=0;r<4;++r){
      int row = n0 + wave*16 + q*4 + r;
      if (row < NN) out[(size_t)row*128 + n*16 + l15] = acc[n][r] + bia;
    }
  }
}

// ---------------- host ------------------------------------------------------
extern "C" void kernel_launch(void* const* d_in, const int* in_sizes, int n_in,
                              void* d_out, int out_size, void* d_ws, size_t ws_size,
                              hipStream_t stream)
{
  const float* node_input = (const float*)d_in[0];
  const float* eattr = (const float*)d_in[2];
  const float* escal = (const float*)d_in[3];
  const int*   esrc  = (const int*)d_in[4];
  const int*   edst  = (const int*)d_in[5];
  const float* wsrc  = (const float*)d_in[7];
  const float* bsrc  = (const float*)d_in[8];
  const float* wdst  = (const float*)d_in[9];
  const float* w1    = (const float*)d_in[10];
  const float* b1    = (const float*)d_in[11];
  const float* w2    = (const float*)d_in[12];
  const float* b2    = (const float*)d_in[13];
  const float* w3    = (const float*)d_in[14];
  const float* b3    = (const float*)d_in[15];
  const float* wsep  = (const float*)d_in[16];
  const float* bsep  = (const float*)d_in[17];
  const float* adot  = (const float*)d_in[18];
  const float* wproj = (const float*)d_in[19];
  const float* bproj = (const float*)d_in[20];

  char* ws = (char*)d_ws;
  size_t off = 0;
  auto alloc = [&](size_t bytes)->void*{ void* p = ws + off; off += (bytes + 255) & ~(size_t)255; return p; };
  u16*   msgsrcB = (u16*)alloc((size_t)NN*128*2);    // 12.8 MB
  u16*   msgdstB = (u16*)alloc((size_t)NN*128*2);    // 12.8 MB
  float* num     = (float*)alloc((size_t)NN*128*4);  // 25.6 MB
  float* denom   = (float*)alloc((size_t)NN*8*4);    //  1.6 MB
  u16* w1T    = (u16*)alloc(2048*2);
  u16* w2T    = (u16*)alloc(4096*2);
  u16* w3T    = (u16*)alloc(8192*2);
  u16* wsepT  = (u16*)alloc(32768*2);
  u16* wsrcT  = (u16*)alloc(16384*2);
  u16* wdstT  = (u16*)alloc(16384*2);
  u16* wprojT = (u16*)alloc(16384*2);
  unsigned* cnt = (unsigned*)alloc((size_t)NN*4);    // 0.2 MB
  unsigned* cur = (unsigned*)alloc((size_t)NN*4);    // 0.2 MB
  unsigned* btot = (unsigned*)alloc(64*4);
  int4*  ework  = (int4*)alloc((size_t)NE*16);       // 12.8 MB
  // total ~66.4 MB (below the 78.8 MB watermark known to fit)

  hipMemsetAsync(num,   0, (size_t)NN*128*4, stream);
  hipMemsetAsync(denom, 0, (size_t)NN*8*4,   stream);
  hipMemsetAsync(cnt,   0, (size_t)NN*4,     stream);

  k_prep_hist<<<3501, 256, 0, stream>>>(w1,w2,w3,wsep,wsrc,wdst,wproj,
                                        w1T,w2T,w3T,wsepT,wsrcT,wdstT,wprojT,
                                        edst, cnt);
  k_scan1<<<49, 1024, 0, stream>>>(cnt, cur, btot);
  k_scan2<<<1, 64, 0, stream>>>(btot);
  k_scatter_node<<<3907, 256, 0, stream>>>(esrc, edst, eattr, cur, btot, ework,
                                           node_input, wsrcT, wdstT, bsrc,
                                           msgsrcB, msgdstB);
  k_edge<<<12500, 256, 0, stream>>>(escal, ework, msgsrcB, msgdstB,
                                    w1T, w2T, w3T, wsepT, b1, b2, b3, bsep, adot,
                                    num, denom);
  k_out<<<782, 256, 0, stream>>>(num, denom, wprojT, bproj, (float*)d_out);
}

// Round 12
// 753.884 us; speedup vs baseline: 1.0993x; 1.0993x over previous
//
#include <hip/hip_runtime.h>

#define NN 50000
#define NE 800000

typedef unsigned short u16;
typedef __bf16 bf16x8 __attribute__((ext_vector_type(8)));
typedef float f32x4 __attribute__((ext_vector_type(4)));
typedef unsigned short u16x8 __attribute__((ext_vector_type(8)));

// native RNE bf16 convert: single v_cvt (pairs get packed to v_cvt_pk_bf16_f32).
__device__ __forceinline__ u16 f2b(float f){
  return __builtin_bit_cast(u16, (__bf16)f);
}
__device__ __forceinline__ float b2f(u16 b){
  return __uint_as_float(((unsigned)b)<<16);
}
// sum over each 16-lane DPP row via rotate-reduce: 4 VALU adds, no LDS pipe.
__device__ __forceinline__ float row_sum16(float x){
  x += __int_as_float(__builtin_amdgcn_update_dpp(0, __float_as_int(x), 0x121, 0xF, 0xF, true));
  x += __int_as_float(__builtin_amdgcn_update_dpp(0, __float_as_int(x), 0x122, 0xF, 0xF, true));
  x += __int_as_float(__builtin_amdgcn_update_dpp(0, __float_as_int(x), 0x124, 0xF, 0xF, true));
  x += __int_as_float(__builtin_amdgcn_update_dpp(0, __float_as_int(x), 0x128, 0xF, 0xF, true));
  return x;
}
#define MFMA16(a,b,c) __builtin_amdgcn_mfma_f32_16x16x32_bf16((a),(b),(c),0,0,0)

// ---------------- K0: fp32 weights -> bf16 [n][k] layout --------------------
__global__ void k_prep(const float* __restrict__ w1, const float* __restrict__ w2,
                       const float* __restrict__ w3, const float* __restrict__ wsep,
                       const float* __restrict__ wsrc, const float* __restrict__ wdst,
                       const float* __restrict__ wproj,
                       u16* __restrict__ w1T, u16* __restrict__ w2T,
                       u16* __restrict__ w3T, u16* __restrict__ wsepT,
                       u16* __restrict__ wsrcT, u16* __restrict__ wdstT,
                       u16* __restrict__ wprojT)
{
  int id = blockIdx.x*256 + threadIdx.x;
  if (id < 2048)  { int n=id>>5,  k=id&31;  w1T[id]   = f2b(w1[k*64+n]);    return; } id -= 2048;
  if (id < 4096)  { int n=id>>6,  k=id&63;  w2T[id]   = f2b(w2[k*64+n]);    return; } id -= 4096;
  if (id < 8192)  { int n=id>>6,  k=id&63;  w3T[id]   = f2b(w3[k*128+n]);   return; } id -= 8192;
  if (id < 32768) { int n=id>>7,  k=id&127; wsepT[id] = f2b(wsep[k*256+n]); return; } id -= 32768;
  if (id < 16384) { int n=id>>7,  k=id&127; wsrcT[id] = f2b(wsrc[k*128+n]); return; } id -= 16384;
  if (id < 16384) { int n=id>>7,  k=id&127; wdstT[id] = f2b(wdst[k*128+n]); return; } id -= 16384;
  if (id < 16384) { int n=id>>7,  k=id&127; wprojT[id]= f2b(wproj[k*128+n]); return; }
}

// ---------------- sort prep: counting sort of edges by dst ------------------
__global__ void k_hist(const int* __restrict__ edst, unsigned* __restrict__ cnt)
{
  int e = blockIdx.x*256 + threadIdx.x;
  if (e < NE) atomicAdd(&cnt[edst[e]], 1u);
}

// 3-kernel parallel scan
__launch_bounds__(1024)
__global__ void k_scan1(const unsigned* __restrict__ cnt, unsigned* __restrict__ cur,
                        unsigned* __restrict__ btot)
{
  __shared__ unsigned wt[16];
  const int tid = threadIdx.x, lane = tid&63, w = tid>>6;
  int i = blockIdx.x*1024 + tid;
  unsigned v = (i < NN) ? cnt[i] : 0u;
  unsigned x = v;
  #pragma unroll
  for (int off=1; off<64; off<<=1){
    unsigned t = __shfl_up(x, off);
    if (lane >= off) x += t;
  }
  if (lane == 63) wt[w] = x;
  __syncthreads();
  if (w == 0){
    unsigned y = (lane < 16) ? wt[lane] : 0u;
    #pragma unroll
    for (int off=1; off<16; off<<=1){
      unsigned t = __shfl_up(y, off);
      if (lane >= off) y += t;
    }
    if (lane < 16) wt[lane] = y;        // inclusive scan of wave totals
  }
  __syncthreads();
  unsigned wo = w ? wt[w-1] : 0u;
  if (i < NN) cur[i] = wo + (x - v);    // block-local exclusive prefix
  if (tid == 1023) btot[blockIdx.x] = wo + x;
}

__global__ void k_scan2(unsigned* __restrict__ btot)
{
  int lane = threadIdx.x;               // single wave of 64
  unsigned v = (lane < 49) ? btot[lane] : 0u;
  unsigned x = v;
  #pragma unroll
  for (int off=1; off<64; off<<=1){
    unsigned t = __shfl_up(x, off);
    if (lane >= off) x += t;
  }
  if (lane < 49) btot[lane] = x - v;    // exclusive, in-place
}

__launch_bounds__(1024)
__global__ void k_scan3(unsigned* __restrict__ cur, const unsigned* __restrict__ btot)
{
  int i = blockIdx.x*1024 + threadIdx.x;
  if (i < NN) cur[i] += btot[blockIdx.x];
}

// AoS edge meta: one random 16B write per edge.
__global__ void k_scatter(const int* __restrict__ esrc, const int* __restrict__ edst,
                          const float* __restrict__ eattr, unsigned* __restrict__ cur,
                          int4* __restrict__ ework)
{
  int e = blockIdx.x*256 + threadIdx.x;
  if (e < NE){
    int d = edst[e];
    unsigned pos = atomicAdd(&cur[d], 1u);
    ework[pos] = make_int4(e, d, esrc[e], __float_as_int(eattr[e]));
  }
}

// ---------------- K1: node GEMM -> bf16 msg buffers -------------------------
__launch_bounds__(256)
__global__ void k_node(const float* __restrict__ x, const u16* __restrict__ wsrcT,
                       const u16* __restrict__ wdstT, const float* __restrict__ bsrc,
                       u16* __restrict__ msgsrcB, u16* __restrict__ msgdstB)
{
  __shared__ u16 sX[64*136];
  __shared__ u16 sW[128*136];
  __shared__ float sB[128];
  const int tid = threadIdx.x;
  const int n0 = blockIdx.x*64;
  for (int idx = tid; idx < 64*32; idx += 256){
    int r = idx>>5, s = idx&31;
    float4 v = make_float4(0.f,0.f,0.f,0.f);
    if (n0 + r < NN) v = *(const float4*)(x + (size_t)(n0+r)*128 + s*4);
    ushort4 o; o.x=f2b(v.x); o.y=f2b(v.y); o.z=f2b(v.z); o.w=f2b(v.w);
    *(ushort4*)(&sX[r*136 + s*4]) = o;
  }
  const int wave = tid>>6, lane = tid&63, l15 = lane&15, q = lane>>4;
  for (int half = 0; half < 2; ++half){
    const u16* wT = half ? wdstT : wsrcT;
    for (int idx = tid; idx < 128*16; idx += 256){
      int r = idx>>4, s = idx&15;
      *(uint4*)(&sW[r*136 + s*8]) = *(const uint4*)(wT + r*128 + s*8);
    }
    if (tid < 128) sB[tid] = half ? 0.0f : bsrc[tid];
    __syncthreads();
    f32x4 acc[8];
    #pragma unroll
    for (int n=0;n<8;++n) acc[n] = (f32x4){0.f,0.f,0.f,0.f};
    #pragma unroll
    for (int k0=0;k0<128;k0+=32){
      bf16x8 a = *(const bf16x8*)(&sX[(wave*16+l15)*136 + k0 + q*8]);
      #pragma unroll
      for (int n=0;n<8;++n){
        bf16x8 b = *(const bf16x8*)(&sW[(n*16+l15)*136 + k0 + q*8]);
        acc[n] = MFMA16(a,b,acc[n]);
      }
    }
    u16* outp = half ? msgdstB : msgsrcB;
    #pragma unroll
    for (int n=0;n<8;++n){
      #pragma unroll
      for (int r=0;r<4;++r){
        int row = n0 + wave*16 + q*4 + r;
        if (row < NN) outp[(size_t)row*128 + n*16 + l15] = f2b(acc[n][r] + sB[n*16+l15]);
      }
    }
    __syncthreads();
  }
}

// ---------------- K2: fused edge kernel (dst-sorted order) ------------------
// EXACT v9 structure (known-good: 455us, FETCH 175MB, WRITE 201MB). All
// scheduling-window edits (barrier removal, fragment hoist, prefetch) are
// confirmed-regressive: the 6 resident blocks' barrier-lockstep cadence is
// what keeps the atomic/gather working set L2-resident.
#define PM 136
#define PH 72
#define PX 40
__launch_bounds__(256,6)
__global__ void k_edge(const float* __restrict__ escal, const int4* __restrict__ ework,
                       const u16* __restrict__ msgsrcB, const u16* __restrict__ msgdstB,
                       const u16* __restrict__ w1T, const u16* __restrict__ w2T,
                       const u16* __restrict__ w3T, const u16* __restrict__ wsepT,
                       const float* __restrict__ b1, const float* __restrict__ b2,
                       const float* __restrict__ b3, const float* __restrict__ bsep,
                       const float* __restrict__ adot,
                       float* __restrict__ num, float* __restrict__ denom)
{
  // liveness-overlaid pool (26624 B -> 6 blocks/CU):
  //   sH1  [0,9216)      written B, read C
  //   sXs  [9216,14336)  written A, read B
  //   sH2  [17408,26624) written C, read D; phase F reuses as sWV[64][34] f32
  //                      (8704 B) + sWp[64][2] f32 (512 B) = 9216 B exactly
  //   sMsg [0,17408)     written D, E in-place, read F
  __shared__ __attribute__((aligned(16))) char pool[26624];
  u16* sH1  = (u16*)(pool + 0);
  u16* sXs  = (u16*)(pool + 9216);
  u16* sH2  = (u16*)(pool + 17408);
  u16* sMsg = (u16*)(pool + 0);

  const int tid = threadIdx.x;
  const int e0 = blockIdx.x*64;
  const int wave = tid>>6, lane = tid&63, l15 = lane&15, q = lane>>4;

  // ---- phase A: stage edge scalars (permuted gather, fp32->bf16)
  for (int j = tid; j < 512; j += 256){ int r=j>>3, s=j&7;
    int pe = ework[e0 + r].x;
    float4 v = *(const float4*)(escal + (size_t)pe*32 + s*4);
    ushort4 o; o.x=f2b(v.x); o.y=f2b(v.y); o.z=f2b(v.z); o.w=f2b(v.w);
    *(ushort4*)&sXs[r*PX + s*4] = o; }
  __syncthreads();

  // ---- phase B: MLP layer1 (K=32) + silu -> sH1 (weights from global)
  {
    f32x4 acc[4];
    #pragma unroll
    for (int n=0;n<4;++n) acc[n] = (f32x4){0.f,0.f,0.f,0.f};
    bf16x8 a = *(const bf16x8*)&sXs[(wave*16+l15)*PX + q*8];
    #pragma unroll
    for (int n=0;n<4;++n){
      bf16x8 b = *(const bf16x8*)(w1T + (n*16+l15)*32 + q*8);
      acc[n] = MFMA16(a,b,acc[n]);
    }
    #pragma unroll
    for (int n=0;n<4;++n){
      float bia = b1[n*16+l15];
      #pragma unroll
      for (int r=0;r<4;++r){
        float v = acc[n][r] + bia;
        float h = v / (1.0f + __expf(-v));
        sH1[(wave*16+q*4+r)*PH + n*16+l15] = f2b(h);
      }
    }
  }
  __syncthreads();

  // ---- phase C: MLP layer2 (K=64) + silu -> sH2 (weights from global)
  {
    f32x4 acc[4];
    #pragma unroll
    for (int n=0;n<4;++n) acc[n] = (f32x4){0.f,0.f,0.f,0.f};
    #pragma unroll
    for (int k0=0;k0<64;k0+=32){
      bf16x8 a = *(const bf16x8*)&sH1[(wave*16+l15)*PH + k0 + q*8];
      #pragma unroll
      for (int n=0;n<4;++n){
        bf16x8 b = *(const bf16x8*)(w2T + (n*16+l15)*64 + k0 + q*8);
        acc[n] = MFMA16(a,b,acc[n]);
      }
    }
    #pragma unroll
    for (int n=0;n<4;++n){
      float bia = b2[n*16+l15];
      #pragma unroll
      for (int r=0;r<4;++r){
        float v = acc[n][r] + bia;
        float h = v / (1.0f + __expf(-v));
        sH2[(wave*16+q*4+r)*PH + n*16+l15] = f2b(h);
      }
    }
  }
  __syncthreads();

  // ---- phase D: MLP layer3 (K=64, 2 chunks of 64 cols) -> rad_w into sMsg
  {
    const int m0 = (wave&1)*2, n0 = (wave>>1)*2;
    #pragma unroll
    for (int ch=0; ch<2; ++ch){
      f32x4 acc[2][2];
      #pragma unroll
      for (int mm=0;mm<2;++mm)
        #pragma unroll
        for (int nn=0;nn<2;++nn) acc[mm][nn] = (f32x4){0.f,0.f,0.f,0.f};
      const u16* w3b = w3T + (size_t)(ch*64)*64;
      #pragma unroll
      for (int k0=0;k0<64;k0+=32){
        bf16x8 a0 = *(const bf16x8*)&sH2[((m0  )*16+l15)*PH + k0 + q*8];
        bf16x8 a1 = *(const bf16x8*)&sH2[((m0+1)*16+l15)*PH + k0 + q*8];
        bf16x8 bb0 = *(const bf16x8*)(w3b + ((n0  )*16+l15)*64 + k0 + q*8);
        bf16x8 bb1 = *(const bf16x8*)(w3b + ((n0+1)*16+l15)*64 + k0 + q*8);
        acc[0][0] = MFMA16(a0,bb0,acc[0][0]);
        acc[1][0] = MFMA16(a1,bb0,acc[1][0]);
        acc[0][1] = MFMA16(a0,bb1,acc[0][1]);
        acc[1][1] = MFMA16(a1,bb1,acc[1][1]);
      }
      #pragma unroll
      for (int mm=0;mm<2;++mm){
        #pragma unroll
        for (int nn=0;nn<2;++nn){
          int c = ch*64 + (n0+nn)*16 + l15;
          float bia = b3[c];
          #pragma unroll
          for (int r=0;r<4;++r){
            float v = acc[mm][nn][r] + bia;
            sMsg[((m0+mm)*16+q*4+r)*PM + c] = f2b(v);
          }
        }
      }
    }
  }
  __syncthreads();

  // ---- phase E: gather node messages (bf16), message = (src+dst)*ea*radw
  for (int idx = tid; idx < 64*16; idx += 256){
    int r = idx>>4, s = idx&15;
    int cs = s*8;
    int4 em = ework[e0 + r];
    int id = em.y, is = em.z;
    float ea = __int_as_float(em.w);
    u16x8 a8 = *(const u16x8*)(msgsrcB + (size_t)is*128 + cs);
    u16x8 d8 = *(const u16x8*)(msgdstB + (size_t)id*128 + cs);
    u16x8 rw = *(const u16x8*)&sMsg[r*PM + cs];
    u16x8 o;
    #pragma unroll
    for (int j=0;j<8;++j){
      o[j] = f2b((b2f(a8[j]) + b2f(d8[j])) * ea * b2f(rw[j]));
    }
    *(u16x8*)&sMsg[r*PM + cs] = o;
  }
  __syncthreads();

  // ---- phase F: message @ w_sep, score->w, then SEGMENTED walk + atomics.
  // No max-subtraction: |score| <~ 5 analytically, exp() safe in fp32, and
  // exp(m) cancels between numerator and denominator as in the reference.
  {
    const int fm0 = (wave&1)*2, fn0 = (wave>>1)*2;
    const int hh = fn0>>1;                      // which head of the ch-pair
    float* sWV = (float*)(pool + 17408);        // [64][34] w*vv (value cols)
    float* sWp = (float*)(pool + 17408 + 8704); // [64][2]  w per (edge, hh)
    const u16* wb0 = wsepT + (size_t)((fn0  )*16+l15)*128 + q*8;
    const u16* wb1 = wsepT + (size_t)((fn0+1)*16+l15)*128 + q*8;
    // walk-role mapping: 8 row-groups x 32 value cols
    const int wc = tid & 31, wg = tid >> 5, wcl = wc & 15, whh = wc >> 4;
    int dreg[8];
    #pragma unroll
    for (int rr=0; rr<8; ++rr) dreg[rr] = ework[e0 + wg*8 + rr].y;

    #pragma unroll
    for (int ch=0; ch<4; ++ch){
      f32x4 acc[2][2];   // [mm][0]=alpha subtile, [mm][1]=value subtile
      #pragma unroll
      for (int mm=0;mm<2;++mm)
        #pragma unroll
        for (int nn=0;nn<2;++nn) acc[mm][nn] = (f32x4){0.f,0.f,0.f,0.f};
      #pragma unroll
      for (int k0=0;k0<128;k0+=32){
        bf16x8 a0 = *(const bf16x8*)&sMsg[((fm0  )*16+l15)*PM + k0 + q*8];
        bf16x8 a1 = *(const bf16x8*)&sMsg[((fm0+1)*16+l15)*PM + k0 + q*8];
        bf16x8 bb0 = *(const bf16x8*)(wb0 + (size_t)ch*64*128 + k0);
        bf16x8 bb1 = *(const bf16x8*)(wb1 + (size_t)ch*64*128 + k0);
        acc[0][0] = MFMA16(a0,bb0,acc[0][0]);
        acc[1][0] = MFMA16(a1,bb0,acc[1][0]);
        acc[0][1] = MFMA16(a0,bb1,acc[0][1]);
        acc[1][1] = MFMA16(a1,bb1,acc[1][1]);
      }
      {
        const int h  = ch*2 + hh;
        const int ca = ch*64 + fn0*16;
        const float ba = bsep[ca + l15];
        const float bv = bsep[ca + 16 + l15];
        const float ad = adot[h*16 + l15];
        #pragma unroll
        for (int mm=0;mm<2;++mm){
          #pragma unroll
          for (int r=0;r<4;++r){
            float av  = acc[mm][0][r] + ba;
            float sig = 1.0f/(1.0f + __expf(-av));
            float sl  = av*(0.2f + 0.8f*sig);       // smooth_leaky_relu(a=0.2)
            float contrib = row_sum16(sl * ad);     // DPP rotate-reduce
            float w  = __expf(contrib);
            float vv = acc[mm][1][r] + bv;
            int row  = (fm0+mm)*16 + q*4 + r;
            sWV[row*34 + hh*16 + l15] = w*vv;
            if (l15 == 0) sWp[row*2 + hh] = w;
          }
        }
      }
      __syncthreads();
      // segmented walk: each thread owns (8-row group, 1 value col); merge
      // runs of equal dst (sorted!) before atomic.
      {
        const int h = ch*2 + whh;
        float av = 0.f, wa = 0.f;
        int pd = dreg[0];
        #pragma unroll
        for (int rr=0; rr<8; ++rr){
          int d = dreg[rr];
          if (d != pd){
            unsafeAtomicAdd(&num[(size_t)pd*128 + h*16 + wcl], av);
            if (wcl == 0) unsafeAtomicAdd(&denom[(size_t)pd*8 + h], wa);
            av = 0.f; wa = 0.f; pd = d;
          }
          int row = wg*8 + rr;
          av += sWV[row*34 + wc];
          if (wcl == 0) wa += sWp[row*2 + whh];
        }
        unsafeAtomicAdd(&num[(size_t)pd*128 + h*16 + wcl], av);
        if (wcl == 0) unsafeAtomicAdd(&denom[(size_t)pd*8 + h], wa);
      }
      __syncthreads();
    }
  }
}

// ---------------- K3: normalize + output projection -------------------------
__launch_bounds__(256)
__global__ void k_out(const float* __restrict__ num, const float* __restrict__ denom,
                      const u16* __restrict__ wprojT, const float* __restrict__ bproj,
                      float* __restrict__ out)
{
  __shared__ u16 sX[64*136];
  __shared__ u16 sW[128*136];
  __shared__ float sB[128];
  const int tid = threadIdx.x;
  const int n0 = blockIdx.x*64;
  for (int idx = tid; idx < 64*128; idx += 256){
    int r = idx>>7, c = idx&127;
    float xv = 0.f;
    int row = n0 + r;
    if (row < NN){
      float d = denom[row*8 + (c>>4)];
      xv = num[(size_t)row*128 + c] / (d + 1e-16f);
    }
    sX[r*136 + c] = f2b(xv);
  }
  for (int idx = tid; idx < 128*16; idx += 256){ int r=idx>>4, s=idx&15;
    *(uint4*)&sW[r*136 + s*8] = *(const uint4*)(wprojT + r*128 + s*8); }
  if (tid < 128) sB[tid] = bproj[tid];
  __syncthreads();
  const int wave = tid>>6, lane = tid&63, l15 = lane&15, q = lane>>4;
  f32x4 acc[8];
  #pragma unroll
  for (int n=0;n<8;++n) acc[n] = (f32x4){0.f,0.f,0.f,0.f};
  #pragma unroll
  for (int k0=0;k0<128;k0+=32){
    bf16x8 a = *(const bf16x8*)&sX[(wave*16+l15)*136 + k0 + q*8];
    #pragma unroll
    for (int n=0;n<8;++n){
      bf16x8 b = *(const bf16x8*)&sW[(n*16+l15)*136 + k0 + q*8];
      acc[n] = MFMA16(a,b,acc[n]);
    }
  }
  #pragma unroll
  for (int n=0;n<8;++n){
    #pragma unroll
    for (int r=0;r<4;++r){
      int row = n0 + wave*16 + q*4 + r;
      if (row < NN) out[(size_t)row*128 + n*16 + l15] = acc[n][r] + sB[n*16+l15];
    }
  }
}

// ---------------- host ------------------------------------------------------
extern "C" void kernel_launch(void* const* d_in, const int* in_sizes, int n_in,
                              void* d_out, int out_size, void* d_ws, size_t ws_size,
                              hipStream_t stream)
{
  const float* node_input = (const float*)d_in[0];
  const float* eattr = (const float*)d_in[2];
  const float* escal = (const float*)d_in[3];
  const int*   esrc  = (const int*)d_in[4];
  const int*   edst  = (const int*)d_in[5];
  const float* wsrc  = (const float*)d_in[7];
  const float* bsrc  = (const float*)d_in[8];
  const float* wdst  = (const float*)d_in[9];
  const float* w1    = (const float*)d_in[10];
  const float* b1    = (const float*)d_in[11];
  const float* w2    = (const float*)d_in[12];
  const float* b2    = (const float*)d_in[13];
  const float* w3    = (const float*)d_in[14];
  const float* b3    = (const float*)d_in[15];
  const float* wsep  = (const float*)d_in[16];
  const float* bsep  = (const float*)d_in[17];
  const float* adot  = (const float*)d_in[18];
  const float* wproj = (const float*)d_in[19];
  const float* bproj = (const float*)d_in[20];

  char* ws = (char*)d_ws;
  size_t off = 0;
  auto alloc = [&](size_t bytes)->void*{ void* p = ws + off; off += (bytes + 255) & ~(size_t)255; return p; };
  u16*   msgsrcB = (u16*)alloc((size_t)NN*128*2);    // 12.8 MB
  u16*   msgdstB = (u16*)alloc((size_t)NN*128*2);    // 12.8 MB
  // num/denom/cnt contiguous (all sizes 256-aligned): ONE memset covers them.
  float* num     = (float*)alloc((size_t)NN*128*4);  // 25.6 MB
  float* denom   = (float*)alloc((size_t)NN*8*4);    //  1.6 MB
  unsigned* cnt  = (unsigned*)alloc((size_t)NN*4);   //  0.2 MB
  u16* w1T    = (u16*)alloc(2048*2);
  u16* w2T    = (u16*)alloc(4096*2);
  u16* w3T    = (u16*)alloc(8192*2);
  u16* wsepT  = (u16*)alloc(32768*2);
  u16* wsrcT  = (u16*)alloc(16384*2);
  u16* wdstT  = (u16*)alloc(16384*2);
  u16* wprojT = (u16*)alloc(16384*2);
  unsigned* cur  = (unsigned*)alloc((size_t)NN*4);   // 0.2 MB
  unsigned* btot = (unsigned*)alloc(64*4);
  int4*  ework  = (int4*)alloc((size_t)NE*16);       // 12.8 MB
  // total ~66.4 MB (below the 78.8 MB watermark known to fit)

  // single memset over num+denom+cnt (contiguous, 27.4 MB): 3 dispatches -> 1
  hipMemsetAsync(num, 0, (size_t)NN*128*4 + (size_t)NN*8*4 + (size_t)NN*4, stream);

  k_prep<<<376, 256, 0, stream>>>(w1,w2,w3,wsep,wsrc,wdst,wproj,
                                  w1T,w2T,w3T,wsepT,wsrcT,wdstT,wprojT);
  k_hist<<<3125, 256, 0, stream>>>(edst, cnt);
  k_scan1<<<49, 1024, 0, stream>>>(cnt, cur, btot);
  k_scan2<<<1, 64, 0, stream>>>(btot);
  k_scan3<<<49, 1024, 0, stream>>>(cur, btot);
  k_scatter<<<3125, 256, 0, stream>>>(esrc, edst, eattr, cur, ework);
  k_node<<<782, 256, 0, stream>>>(node_input, wsrcT, wdstT, bsrc, msgsrcB, msgdstB);
  k_edge<<<12500, 256, 0, stream>>>(escal, ework, msgsrcB, msgdstB,
                                    w1T, w2T, w3T, wsepT, b1, b2, b3, bsep, adot,
                                    num, denom);
  k_out<<<782, 256, 0, stream>>>(num, denom, wprojT, bproj, (float*)d_out);
}